// Round 1
// baseline (10786.526 us; speedup 1.0000x reference)
//
#include <hip/hip_runtime.h>
#include <hip/hip_bf16.h>
#include <math.h>

// Problem constants (from reference)
#define BATCH 2048
#define TLEN 100
#define SMH 256
#define HID 1024
#define EMBD 64
#define VOCAB 100
#define PADLEN 45

// ---------------------------------------------------------------------------
// init: tok = 0 (sos), decoded row 0 = 0.0f
// ---------------------------------------------------------------------------
__global__ __launch_bounds__(256) void init_kernel(int* tok, float* dec0) {
    int idx = blockIdx.x * 256 + threadIdx.x;
    if (idx < BATCH) {
        tok[idx] = 0;
        dec0[idx] = 0.0f;
    }
}

// ---------------------------------------------------------------------------
// feats: concat(max_t, mean_t) of sm_hidden[B, T, SMH] -> feats[B, 2*SMH]
// one block per b, thread c handles channel c
// ---------------------------------------------------------------------------
__global__ __launch_bounds__(256) void feats_kernel(const float* __restrict__ sm,
                                                    float* __restrict__ feats) {
    int b = blockIdx.x;
    int c = threadIdx.x;  // 0..255
    const float* p = sm + (long)b * TLEN * SMH + c;
    float mx = -INFINITY;
    float s = 0.0f;
#pragma unroll 4
    for (int t = 0; t < TLEN; t++) {
        float v = p[(long)t * SMH];
        mx = fmaxf(mx, v);
        s += v;
    }
    feats[(long)b * (2 * SMH) + c] = mx;
    feats[(long)b * (2 * SMH) + SMH + c] = s * (1.0f / TLEN);
}

// ---------------------------------------------------------------------------
// gx precompute: gx[v][j] = dot(relu(emb[v]), Wi[j]) + bi[j]
// grid: (3072/256, 100)
// ---------------------------------------------------------------------------
__global__ __launch_bounds__(256) void gx_kernel(const float* __restrict__ emb,
                                                 const float* __restrict__ Wi,
                                                 const float* __restrict__ bi,
                                                 float* __restrict__ gx) {
    __shared__ float x[EMBD];
    int v = blockIdx.y;
    int j = blockIdx.x * 256 + threadIdx.x;  // 0..3071
    if (threadIdx.x < EMBD) x[threadIdx.x] = fmaxf(emb[v * EMBD + threadIdx.x], 0.0f);
    __syncthreads();
    const float* w = Wi + (long)j * EMBD;
    float acc = 0.0f;
#pragma unroll
    for (int k = 0; k < EMBD; k++) acc += x[k] * w[k];
    gx[(long)v * (3 * HID) + j] = acc + bi[j];
}

// ---------------------------------------------------------------------------
// transpose W_out[V,H] -> Wt[H,V]
// ---------------------------------------------------------------------------
__global__ __launch_bounds__(256) void transpose_wout(const float* __restrict__ W_out,
                                                      float* __restrict__ Wt) {
    int idx = blockIdx.x * 256 + threadIdx.x;
    if (idx < HID * VOCAB) {
        int k = idx / VOCAB;
        int w = idx % VOCAB;
        Wt[idx] = W_out[(long)w * HID + k];
    }
}

// ---------------------------------------------------------------------------
// fp32 GEMM: C[M,N] = A[M,K] @ B[N,K]^T + bias[N], optional relu.
// 128x128 tile, BK=16, 256 threads, 8x8 micro-tile (split 4+4 halves).
// M, N divisible by 128; K divisible by 16.
// ---------------------------------------------------------------------------
#define LSTR 132  // padded LDS row stride

__global__ __launch_bounds__(256) void gemm_abT(const float* __restrict__ A,
                                                const float* __restrict__ B,
                                                const float* __restrict__ bias,
                                                float* __restrict__ C,
                                                int M, int N, int K, int do_relu) {
    __shared__ float As[16][LSTR];
    __shared__ float Bs[16][LSTR];

    int tid = threadIdx.x;
    int m0 = blockIdx.y * 128;
    int n0 = blockIdx.x * 128;
    int tx = tid & 15;   // 0..15 -> col groups tx*4 and 64+tx*4
    int ty = tid >> 4;   // 0..15 -> row groups ty*4 and 64+ty*4

    int lr = tid >> 2;         // 0..63 (loader row)
    int lk = (tid & 3) * 4;    // 0,4,8,12 (loader k offset)

    const float* Aptr = A + (long)(m0 + lr) * K + lk;
    const float* Bptr = B + (long)(n0 + lr) * K + lk;

    float acc[8][8];
#pragma unroll
    for (int i = 0; i < 8; i++)
#pragma unroll
        for (int j = 0; j < 8; j++) acc[i][j] = 0.0f;

    for (int k0 = 0; k0 < K; k0 += 16) {
        float4 a0 = *(const float4*)(Aptr + k0);
        float4 a1 = *(const float4*)(Aptr + (long)64 * K + k0);
        float4 b0 = *(const float4*)(Bptr + k0);
        float4 b1 = *(const float4*)(Bptr + (long)64 * K + k0);
        __syncthreads();
        As[lk + 0][lr] = a0.x; As[lk + 1][lr] = a0.y; As[lk + 2][lr] = a0.z; As[lk + 3][lr] = a0.w;
        As[lk + 0][lr + 64] = a1.x; As[lk + 1][lr + 64] = a1.y; As[lk + 2][lr + 64] = a1.z; As[lk + 3][lr + 64] = a1.w;
        Bs[lk + 0][lr] = b0.x; Bs[lk + 1][lr] = b0.y; Bs[lk + 2][lr] = b0.z; Bs[lk + 3][lr] = b0.w;
        Bs[lk + 0][lr + 64] = b1.x; Bs[lk + 1][lr + 64] = b1.y; Bs[lk + 2][lr + 64] = b1.z; Bs[lk + 3][lr + 64] = b1.w;
        __syncthreads();

#pragma unroll
        for (int kk = 0; kk < 16; kk++) {
            float4 av0 = *(const float4*)&As[kk][ty * 4];
            float4 av1 = *(const float4*)&As[kk][64 + ty * 4];
            float4 bv0 = *(const float4*)&Bs[kk][tx * 4];
            float4 bv1 = *(const float4*)&Bs[kk][64 + tx * 4];
            float am[8] = {av0.x, av0.y, av0.z, av0.w, av1.x, av1.y, av1.z, av1.w};
            float bn[8] = {bv0.x, bv0.y, bv0.z, bv0.w, bv1.x, bv1.y, bv1.z, bv1.w};
#pragma unroll
            for (int i = 0; i < 8; i++)
#pragma unroll
                for (int j = 0; j < 8; j++) acc[i][j] += am[i] * bn[j];
        }
    }

    // epilogue
#pragma unroll
    for (int ih = 0; ih < 2; ih++) {
#pragma unroll
        for (int i = 0; i < 4; i++) {
            int row = m0 + ih * 64 + ty * 4 + i;
#pragma unroll
            for (int jh = 0; jh < 2; jh++) {
                int col = n0 + jh * 64 + tx * 4;
                float4 v;
                v.x = acc[ih * 4 + i][jh * 4 + 0] + bias[col + 0];
                v.y = acc[ih * 4 + i][jh * 4 + 1] + bias[col + 1];
                v.z = acc[ih * 4 + i][jh * 4 + 2] + bias[col + 2];
                v.w = acc[ih * 4 + i][jh * 4 + 3] + bias[col + 3];
                if (do_relu) {
                    v.x = fmaxf(v.x, 0.0f); v.y = fmaxf(v.y, 0.0f);
                    v.z = fmaxf(v.z, 0.0f); v.w = fmaxf(v.w, 0.0f);
                }
                *(float4*)(C + (long)row * N + col) = v;
            }
        }
    }
}

// ---------------------------------------------------------------------------
// GRU elementwise: h_new from gh, gx[tok], h ; writes h (in-place) and rnn_out
// ---------------------------------------------------------------------------
__device__ __forceinline__ float sigmoidf(float x) {
    return 1.0f / (1.0f + expf(-x));
}

__global__ __launch_bounds__(256) void gru_elem(const float* __restrict__ gh,
                                                const float* __restrict__ gx,
                                                const int* __restrict__ tok,
                                                float* __restrict__ h,
                                                float* __restrict__ rnn,  // d_out rnn base
                                                int t) {
    int idx = blockIdx.x * 256 + threadIdx.x;
    int b = idx >> 10;         // /1024
    int j = idx & 1023;        // %1024
    int tk = tok[b];
    const float* g = gx + (long)tk * (3 * HID);
    float ir = g[j];
    float iz = g[HID + j];
    float in_ = g[2 * HID + j];
    const float* ghb = gh + (long)b * (3 * HID);
    float hr = ghb[j];
    float hz = ghb[HID + j];
    float hn = ghb[2 * HID + j];
    float hp = h[(long)b * HID + j];
    float r = sigmoidf(ir + hr);
    float z = sigmoidf(iz + hz);
    float n = fmaxf(in_ + r * hn, 0.0f);
    float hnew = (1.0f - z) * n + z * hp;
    h[(long)b * HID + j] = hnew;
    rnn[(long)b * (PADLEN * HID) + (long)t * HID + j] = hnew;
}

// ---------------------------------------------------------------------------
// logits + argmax: per block 4 batch rows; 256 threads = 2 k-splits x 128 w.
// writes tok[b], decoded row (t+1), and logits (for final log_softmax).
// ---------------------------------------------------------------------------
__global__ __launch_bounds__(256) void logits_argmax(const float* __restrict__ h,
                                                     const float* __restrict__ Wt,
                                                     const float* __restrict__ b_out,
                                                     int* __restrict__ tok,
                                                     float* __restrict__ dec_row,
                                                     float* __restrict__ logits_out) {
    __shared__ float hs[4 * HID];       // 16 KB
    __shared__ float part[2][4][128];   // 4 KB
    __shared__ float lg[4][100];

    int tid = threadIdx.x;
    int b0 = blockIdx.x * 4;

    // stage 4 h rows
    const float4* hsrc = (const float4*)(h + (long)b0 * HID);
    float4* hdst = (float4*)hs;
    for (int i = tid; i < HID; i += 256) hdst[i] = hsrc[i];
    __syncthreads();

    int s = tid >> 7;      // 0..1 k-split
    int w = tid & 127;     // word (active < 100)
    float a0 = 0.f, a1 = 0.f, a2 = 0.f, a3 = 0.f;
    if (w < VOCAB) {
        const float* wp = Wt + (long)s * 512 * VOCAB + w;
        int kb = s * 512;
#pragma unroll 4
        for (int k = 0; k < 512; k++) {
            float wv = wp[(long)k * VOCAB];
            int kk = kb + k;
            a0 += hs[0 * HID + kk] * wv;
            a1 += hs[1 * HID + kk] * wv;
            a2 += hs[2 * HID + kk] * wv;
            a3 += hs[3 * HID + kk] * wv;
        }
    }
    part[s][0][w] = a0;
    part[s][1][w] = a1;
    part[s][2][w] = a2;
    part[s][3][w] = a3;
    __syncthreads();

    if (s == 0 && w < VOCAB) {
#pragma unroll
        for (int r = 0; r < 4; r++) {
            float lv = part[0][r][w] + part[1][r][w] + b_out[w];
            lg[r][w] = lv;
            logits_out[(long)(b0 + r) * VOCAB + w] = lv;
        }
    }
    __syncthreads();

    // argmax: wave per row, first-index tie-break
    int wave = tid >> 6;
    int lane = tid & 63;
    int r = wave;
    float v = (lane < VOCAB) ? lg[r][lane] : -INFINITY;
    int idx = lane;
    if (lane + 64 < VOCAB) {
        float v2 = lg[r][lane + 64];
        if (v2 > v) { v = v2; idx = lane + 64; }
    }
#pragma unroll
    for (int off = 32; off > 0; off >>= 1) {
        float vo = __shfl_xor(v, off);
        int io = __shfl_xor(idx, off);
        if (vo > v || (vo == v && io < idx)) { v = vo; idx = io; }
    }
    if (lane == 0) {
        tok[b0 + r] = idx;
        dec_row[b0 + r] = (float)idx;
    }
}

// ---------------------------------------------------------------------------
// log_softmax over last logits [B, V] -> d_out[0 .. B*V)
// wave per row
// ---------------------------------------------------------------------------
__global__ __launch_bounds__(256) void log_softmax_k(const float* __restrict__ logits,
                                                     float* __restrict__ out) {
    int wave = threadIdx.x >> 6;
    int lane = threadIdx.x & 63;
    int b = blockIdx.x * 4 + wave;
    const float* lp = logits + (long)b * VOCAB;
    float v1 = (lane < VOCAB) ? lp[lane] : -INFINITY;
    float v2 = (lane + 64 < VOCAB) ? lp[lane + 64] : -INFINITY;
    float m = fmaxf(v1, v2);
#pragma unroll
    for (int off = 32; off > 0; off >>= 1) m = fmaxf(m, __shfl_xor(m, off));
    float e = ((lane < VOCAB) ? expf(v1 - m) : 0.0f) + ((lane + 64 < VOCAB) ? expf(v2 - m) : 0.0f);
#pragma unroll
    for (int off = 32; off > 0; off >>= 1) e += __shfl_xor(e, off);
    float ls = logf(e);
    if (lane < VOCAB) out[(long)b * VOCAB + lane] = v1 - m - ls;
    if (lane + 64 < VOCAB) out[(long)b * VOCAB + lane + 64] = v2 - m - ls;
}

// ---------------------------------------------------------------------------
extern "C" void kernel_launch(void* const* d_in, const int* in_sizes, int n_in,
                              void* d_out, int out_size, void* d_ws, size_t ws_size,
                              hipStream_t stream) {
    const float* sm    = (const float*)d_in[0];
    const float* emb   = (const float*)d_in[1];
    const float* W_fc1 = (const float*)d_in[2];
    const float* b_fc1 = (const float*)d_in[3];
    const float* Wi    = (const float*)d_in[4];
    const float* Wh    = (const float*)d_in[5];
    const float* bi    = (const float*)d_in[6];
    const float* bh    = (const float*)d_in[7];
    const float* W_out = (const float*)d_in[8];
    const float* b_out = (const float*)d_in[9];
    float* out = (float*)d_out;

    // workspace layout (floats)
    float* ws = (float*)d_ws;
    float* feats  = ws;                          // 2048*512   = 1,048,576
    float* h      = feats + (long)BATCH * 512;   // 2048*1024  = 2,097,152
    float* gh     = h + (long)BATCH * HID;       // 2048*3072  = 6,291,456
    float* gx     = gh + (long)BATCH * 3 * HID;  // 100*3072   = 307,200
    float* Wt     = gx + (long)VOCAB * 3 * HID;  // 1024*100   = 102,400
    float* logits = Wt + (long)HID * VOCAB;      // 2048*100   = 204,800
    int*   tok    = (int*)(logits + (long)BATCH * VOCAB);  // 2048 ints

    // output layout (floats)
    float* logp = out;                                   // [2048,100]
    float* rnn  = out + (long)BATCH * VOCAB;             // [2048,45,1024]
    float* dec  = rnn + (long)BATCH * PADLEN * HID;      // [46,2048]

    // prep
    init_kernel<<<(BATCH + 255) / 256, 256, 0, stream>>>(tok, dec);
    feats_kernel<<<BATCH, 256, 0, stream>>>(sm, feats);
    gemm_abT<<<dim3(HID / 128, BATCH / 128), 256, 0, stream>>>(feats, W_fc1, b_fc1, h,
                                                               BATCH, HID, 2 * SMH, 1);
    gx_kernel<<<dim3(3 * HID / 256, VOCAB), 256, 0, stream>>>(emb, Wi, bi, gx);
    transpose_wout<<<(HID * VOCAB + 255) / 256, 256, 0, stream>>>(W_out, Wt);

    // recurrent loop
    for (int t = 0; t < PADLEN; t++) {
        gemm_abT<<<dim3(3 * HID / 128, BATCH / 128), 256, 0, stream>>>(h, Wh, bh, gh,
                                                                       BATCH, 3 * HID, HID, 0);
        gru_elem<<<(BATCH * HID) / 256, 256, 0, stream>>>(gh, gx, tok, h, rnn, t);
        logits_argmax<<<BATCH / 4, 256, 0, stream>>>(h, Wt, b_out, tok,
                                                     dec + (long)(t + 1) * BATCH, logits);
    }

    // final log_softmax
    log_softmax_k<<<BATCH / 4, 256, 0, stream>>>(logits, logp);
}

// Round 2
// 5683.652 us; speedup vs baseline: 1.8978x; 1.8978x over previous
//
#include <hip/hip_runtime.h>
#include <hip/hip_bf16.h>
#include <math.h>

// Problem constants (from reference)
#define BATCH 2048
#define TLEN 100
#define SMH 256
#define HID 1024
#define EMBD 64
#define VOCAB 100
#define PADLEN 45

typedef float  float4v __attribute__((ext_vector_type(4)));
typedef short  short8v __attribute__((ext_vector_type(8)));

// ---------------------------------------------------------------------------
// bf16 split helpers: x ~= hi + lo, each bf16 (RNE)
// ---------------------------------------------------------------------------
__device__ __forceinline__ unsigned short f2bf(float x) {
    unsigned u = __float_as_uint(x);
    u += 0x7fffu + ((u >> 16) & 1u);
    return (unsigned short)(u >> 16);
}
__device__ __forceinline__ float bf2f(unsigned short h) {
    return __uint_as_float(((unsigned)h) << 16);
}
__device__ __forceinline__ void split_bf(float x, unsigned short* hi, unsigned short* lo) {
    unsigned short h = f2bf(x);
    *hi = h;
    *lo = f2bf(x - bf2f(h));
}

// async 16B/lane global->LDS (dest = base + lane*16)
__device__ __forceinline__ void async16(const unsigned short* g, unsigned short* l) {
    __builtin_amdgcn_global_load_lds(
        (const __attribute__((address_space(1))) void*)g,
        (__attribute__((address_space(3))) void*)l,
        16, 0, 0);
}

// ---------------------------------------------------------------------------
// init: tok = 0 (sos), decoded row 0 = 0.0f
// ---------------------------------------------------------------------------
__global__ __launch_bounds__(256) void init_kernel(int* tok, float* dec0) {
    int idx = blockIdx.x * 256 + threadIdx.x;
    if (idx < BATCH) {
        tok[idx] = 0;
        dec0[idx] = 0.0f;
    }
}

// ---------------------------------------------------------------------------
// feats: concat(max_t, mean_t) -> split bf16 directly (fh/fl [B][512])
// ---------------------------------------------------------------------------
__global__ __launch_bounds__(256) void feats_split_kernel(const float* __restrict__ sm,
                                                          unsigned short* __restrict__ fh,
                                                          unsigned short* __restrict__ fl) {
    int b = blockIdx.x;
    int c = threadIdx.x;  // 0..255
    const float* p = sm + (long)b * TLEN * SMH + c;
    float mx = -INFINITY;
    float s = 0.0f;
#pragma unroll 4
    for (int t = 0; t < TLEN; t++) {
        float v = p[(long)t * SMH];
        mx = fmaxf(mx, v);
        s += v;
    }
    float mn = s * (1.0f / TLEN);
    unsigned short h1, l1, h2, l2;
    split_bf(mx, &h1, &l1);
    split_bf(mn, &h2, &l2);
    long base = (long)b * (2 * SMH);
    fh[base + c] = h1;       fl[base + c] = l1;
    fh[base + SMH + c] = h2; fl[base + SMH + c] = l2;
}

// ---------------------------------------------------------------------------
// generic fp32 -> (hi, lo) bf16 split
// ---------------------------------------------------------------------------
__global__ __launch_bounds__(256) void split_kernel(const float* __restrict__ in,
                                                    unsigned short* __restrict__ hi,
                                                    unsigned short* __restrict__ lo, long n) {
    long i = (long)blockIdx.x * 256 + threadIdx.x;
    if (i < n) {
        unsigned short h, l;
        split_bf(in[i], &h, &l);
        hi[i] = h;
        lo[i] = l;
    }
}

// ---------------------------------------------------------------------------
// gx precompute: gx[v][j] = dot(relu(emb[v]), Wi[j]) + bi[j]   (fp32, exact)
// ---------------------------------------------------------------------------
__global__ __launch_bounds__(256) void gx_kernel(const float* __restrict__ emb,
                                                 const float* __restrict__ Wi,
                                                 const float* __restrict__ bi,
                                                 float* __restrict__ gx) {
    __shared__ float x[EMBD];
    int v = blockIdx.y;
    int j = blockIdx.x * 256 + threadIdx.x;
    if (threadIdx.x < EMBD) x[threadIdx.x] = fmaxf(emb[v * EMBD + threadIdx.x], 0.0f);
    __syncthreads();
    const float* w = Wi + (long)j * EMBD;
    float acc = 0.0f;
#pragma unroll
    for (int k = 0; k < EMBD; k++) acc += x[k] * w[k];
    gx[(long)v * (3 * HID) + j] = acc + bi[j];
}

// ---------------------------------------------------------------------------
// transpose W_out[V,H] -> Wt[H,V]
// ---------------------------------------------------------------------------
__global__ __launch_bounds__(256) void transpose_wout(const float* __restrict__ W_out,
                                                      float* __restrict__ Wt) {
    int idx = blockIdx.x * 256 + threadIdx.x;
    if (idx < HID * VOCAB) {
        int k = idx / VOCAB;
        int w = idx % VOCAB;
        Wt[idx] = W_out[(long)w * HID + k];
    }
}

// ---------------------------------------------------------------------------
// split-bf16 MFMA GEMM: C[M,N] = A[M,K] @ B[N,K]^T + bias[N]
//   A given as (Ah, Al) bf16 pair, B as (Bh, Bl); product via 3 MFMAs:
//   Ah*Bh + Ah*Bl + Al*Bh  (~fp32 accuracy, fp32 accumulate).
// 128x128 tile, BK=32, 256 threads = 4 waves (2x2), wave = 4x4 of 16x16x32.
// LDS holds fragment-order tiles staged by global_load_lds (16B/lane):
//   tile t (16 rows), lane L: row = t*16 + (L&15), k = 8*(L>>4)..+7
// -> ds_read_b128 at base + lane*16: lane-linear, conflict-free.
// Optional split output (Ch/Cl) for feeding the next GEMM.
// M%128==0, N%128==0, K%32==0.
// ---------------------------------------------------------------------------
__global__ __launch_bounds__(256) void gemm_mfma_split(
    const unsigned short* __restrict__ Ah, const unsigned short* __restrict__ Al,
    const unsigned short* __restrict__ Bh, const unsigned short* __restrict__ Bl,
    const float* __restrict__ bias, float* __restrict__ C,
    unsigned short* __restrict__ Ch, unsigned short* __restrict__ Cl,
    int M, int N, int K, int do_relu) {
    __shared__ unsigned short lAh[4096];  // 8 tiles x 512 ushort (8KB)
    __shared__ unsigned short lAl[4096];
    __shared__ unsigned short lBh[4096];
    __shared__ unsigned short lBl[4096];

    int tid = threadIdx.x;
    int wave = tid >> 6;
    int lane = tid & 63;
    int m0 = blockIdx.y * 128;
    int n0 = blockIdx.x * 128;
    int srow = lane & 15;          // staging row within 16-row tile
    int skg = (lane >> 4) * 8;     // staging k offset (8 bf16 = 16B)
    int wm = wave & 1;             // wave m-half
    int wn = wave >> 1;            // wave n-half

    float4v acc[4][4];
#pragma unroll
    for (int i = 0; i < 4; i++)
#pragma unroll
        for (int j = 0; j < 4; j++) acc[i][j] = (float4v){0.0f, 0.0f, 0.0f, 0.0f};

    for (int k0 = 0; k0 < K; k0 += 32) {
        // stage: each wave stages tiles {2w, 2w+1} of all 4 layers
#pragma unroll
        for (int i = 0; i < 2; i++) {
            int t = wave * 2 + i;
            long ga = (long)(m0 + t * 16 + srow) * K + k0 + skg;
            long gb = (long)(n0 + t * 16 + srow) * K + k0 + skg;
            async16(Ah + ga, &lAh[t * 512]);
            async16(Al + ga, &lAl[t * 512]);
            async16(Bh + gb, &lBh[t * 512]);
            async16(Bl + gb, &lBl[t * 512]);
        }
        __syncthreads();  // drains vmcnt, staging visible

        const short8v* pAh = (const short8v*)lAh;
        const short8v* pAl = (const short8v*)lAl;
        const short8v* pBh = (const short8v*)lBh;
        const short8v* pBl = (const short8v*)lBl;
        short8v afh[4], afl[4], bfh[4], bfl[4];
#pragma unroll
        for (int i = 0; i < 4; i++) {
            afh[i] = pAh[(wm * 4 + i) * 64 + lane];
            afl[i] = pAl[(wm * 4 + i) * 64 + lane];
            bfh[i] = pBh[(wn * 4 + i) * 64 + lane];
            bfl[i] = pBl[(wn * 4 + i) * 64 + lane];
        }
#pragma unroll
        for (int i = 0; i < 4; i++)
#pragma unroll
            for (int j = 0; j < 4; j++) {
                acc[i][j] = __builtin_amdgcn_mfma_f32_16x16x32_bf16(afh[i], bfh[j], acc[i][j], 0, 0, 0);
                acc[i][j] = __builtin_amdgcn_mfma_f32_16x16x32_bf16(afh[i], bfl[j], acc[i][j], 0, 0, 0);
                acc[i][j] = __builtin_amdgcn_mfma_f32_16x16x32_bf16(afl[i], bfh[j], acc[i][j], 0, 0, 0);
            }
        __syncthreads();  // protect LDS before next stage
    }

    // epilogue: C/D layout col = lane&15, row = (lane>>4)*4 + reg  [m89-verified]
    int er = (lane >> 4) * 4;
    int ec = lane & 15;
#pragma unroll
    for (int i = 0; i < 4; i++) {
        int row0 = m0 + (wm * 4 + i) * 16 + er;
#pragma unroll
        for (int j = 0; j < 4; j++) {
            int col = n0 + (wn * 4 + j) * 16 + ec;
            float bv = bias[col];
#pragma unroll
            for (int r = 0; r < 4; r++) {
                float v = acc[i][j][r] + bv;
                if (do_relu) v = fmaxf(v, 0.0f);
                long off = (long)(row0 + r) * N + col;
                C[off] = v;
                if (Ch) {
                    unsigned short hh_, ll_;
                    split_bf(v, &hh_, &ll_);
                    Ch[off] = hh_;
                    Cl[off] = ll_;
                }
            }
        }
    }
}

// ---------------------------------------------------------------------------
// GRU elementwise: h_new from gh, gx[tok], h ; writes h fp32 + split (hh,hl)
// + rnn_out slice
// ---------------------------------------------------------------------------
__device__ __forceinline__ float sigmoidf(float x) {
    return 1.0f / (1.0f + expf(-x));
}

__global__ __launch_bounds__(256) void gru_elem(const float* __restrict__ gh,
                                                const float* __restrict__ gx,
                                                const int* __restrict__ tok,
                                                float* __restrict__ h,
                                                unsigned short* __restrict__ hh,
                                                unsigned short* __restrict__ hl,
                                                float* __restrict__ rnn, int t) {
    int idx = blockIdx.x * 256 + threadIdx.x;
    int b = idx >> 10;
    int j = idx & 1023;
    int tk = tok[b];
    const float* g = gx + (long)tk * (3 * HID);
    float ir = g[j];
    float iz = g[HID + j];
    float in_ = g[2 * HID + j];
    const float* ghb = gh + (long)b * (3 * HID);
    float hr = ghb[j];
    float hz = ghb[HID + j];
    float hn = ghb[2 * HID + j];
    float hp = h[(long)b * HID + j];
    float r = sigmoidf(ir + hr);
    float z = sigmoidf(iz + hz);
    float n = fmaxf(in_ + r * hn, 0.0f);
    float hnew = (1.0f - z) * n + z * hp;
    long off = (long)b * HID + j;
    h[off] = hnew;
    rnn[(long)b * (PADLEN * HID) + (long)t * HID + j] = hnew;
    unsigned short sh, sl;
    split_bf(hnew, &sh, &sl);
    hh[off] = sh;
    hl[off] = sl;
}

// ---------------------------------------------------------------------------
// logits + argmax: per block 4 batch rows; 256 threads = 2 k-splits x 128 w.
// ---------------------------------------------------------------------------
__global__ __launch_bounds__(256) void logits_argmax(const float* __restrict__ h,
                                                     const float* __restrict__ Wt,
                                                     const float* __restrict__ b_out,
                                                     int* __restrict__ tok,
                                                     float* __restrict__ dec_row,
                                                     float* __restrict__ logits_out) {
    __shared__ float hs[4 * HID];
    __shared__ float part[2][4][128];
    __shared__ float lg[4][100];

    int tid = threadIdx.x;
    int b0 = blockIdx.x * 4;

    const float4* hsrc = (const float4*)(h + (long)b0 * HID);
    float4* hdst = (float4*)hs;
    for (int i = tid; i < HID; i += 256) hdst[i] = hsrc[i];
    __syncthreads();

    int s = tid >> 7;
    int w = tid & 127;
    float a0 = 0.f, a1 = 0.f, a2 = 0.f, a3 = 0.f;
    if (w < VOCAB) {
        const float* wp = Wt + (long)s * 512 * VOCAB + w;
        int kb = s * 512;
#pragma unroll 4
        for (int k = 0; k < 512; k++) {
            float wv = wp[(long)k * VOCAB];
            int kk = kb + k;
            a0 += hs[0 * HID + kk] * wv;
            a1 += hs[1 * HID + kk] * wv;
            a2 += hs[2 * HID + kk] * wv;
            a3 += hs[3 * HID + kk] * wv;
        }
    }
    part[s][0][w] = a0;
    part[s][1][w] = a1;
    part[s][2][w] = a2;
    part[s][3][w] = a3;
    __syncthreads();

    if (s == 0 && w < VOCAB) {
#pragma unroll
        for (int r = 0; r < 4; r++) {
            float lv = part[0][r][w] + part[1][r][w] + b_out[w];
            lg[r][w] = lv;
            logits_out[(long)(b0 + r) * VOCAB + w] = lv;
        }
    }
    __syncthreads();

    int wave = tid >> 6;
    int lane = tid & 63;
    int r = wave;
    float v = (lane < VOCAB) ? lg[r][lane] : -INFINITY;
    int idx = lane;
    if (lane + 64 < VOCAB) {
        float v2 = lg[r][lane + 64];
        if (v2 > v) { v = v2; idx = lane + 64; }
    }
#pragma unroll
    for (int off = 32; off > 0; off >>= 1) {
        float vo = __shfl_xor(v, off);
        int io = __shfl_xor(idx, off);
        if (vo > v || (vo == v && io < idx)) { v = vo; idx = io; }
    }
    if (lane == 0) {
        tok[b0 + r] = idx;
        dec_row[b0 + r] = (float)idx;
    }
}

// ---------------------------------------------------------------------------
// log_softmax over last logits [B, V]
// ---------------------------------------------------------------------------
__global__ __launch_bounds__(256) void log_softmax_k(const float* __restrict__ logits,
                                                     float* __restrict__ out) {
    int wave = threadIdx.x >> 6;
    int lane = threadIdx.x & 63;
    int b = blockIdx.x * 4 + wave;
    const float* lp = logits + (long)b * VOCAB;
    float v1 = (lane < VOCAB) ? lp[lane] : -INFINITY;
    float v2 = (lane + 64 < VOCAB) ? lp[lane + 64] : -INFINITY;
    float m = fmaxf(v1, v2);
#pragma unroll
    for (int off = 32; off > 0; off >>= 1) m = fmaxf(m, __shfl_xor(m, off));
    float e = ((lane < VOCAB) ? expf(v1 - m) : 0.0f) + ((lane + 64 < VOCAB) ? expf(v2 - m) : 0.0f);
#pragma unroll
    for (int off = 32; off > 0; off >>= 1) e += __shfl_xor(e, off);
    float ls = logf(e);
    if (lane < VOCAB) out[(long)b * VOCAB + lane] = v1 - m - ls;
    if (lane + 64 < VOCAB) out[(long)b * VOCAB + lane + 64] = v2 - m - ls;
}

// ---------------------------------------------------------------------------
extern "C" void kernel_launch(void* const* d_in, const int* in_sizes, int n_in,
                              void* d_out, int out_size, void* d_ws, size_t ws_size,
                              hipStream_t stream) {
    const float* sm    = (const float*)d_in[0];
    const float* emb   = (const float*)d_in[1];
    const float* W_fc1 = (const float*)d_in[2];
    const float* b_fc1 = (const float*)d_in[3];
    const float* Wi    = (const float*)d_in[4];
    const float* Wh    = (const float*)d_in[5];
    const float* bi    = (const float*)d_in[6];
    const float* bh    = (const float*)d_in[7];
    const float* W_out = (const float*)d_in[8];
    const float* b_out = (const float*)d_in[9];
    float* out = (float*)d_out;

    // workspace carve-up (256B aligned)
    char* wsp = (char*)d_ws;
    auto carve = [&](size_t bytes) {
        char* p = wsp;
        wsp += (bytes + 255) & ~(size_t)255;
        return p;
    };
    unsigned short* Whh = (unsigned short*)carve((size_t)3 * HID * HID * 2);
    unsigned short* Whl = (unsigned short*)carve((size_t)3 * HID * HID * 2);
    unsigned short* W1h = (unsigned short*)carve((size_t)HID * 2 * SMH * 2);
    unsigned short* W1l = (unsigned short*)carve((size_t)HID * 2 * SMH * 2);
    unsigned short* fh  = (unsigned short*)carve((size_t)BATCH * 2 * SMH * 2);
    unsigned short* fl  = (unsigned short*)carve((size_t)BATCH * 2 * SMH * 2);
    float* h   = (float*)carve((size_t)BATCH * HID * 4);
    unsigned short* hh = (unsigned short*)carve((size_t)BATCH * HID * 2);
    unsigned short* hl = (unsigned short*)carve((size_t)BATCH * HID * 2);
    float* gh_buf = (float*)carve((size_t)BATCH * 3 * HID * 4);
    float* gx  = (float*)carve((size_t)VOCAB * 3 * HID * 4);
    float* Wt  = (float*)carve((size_t)HID * VOCAB * 4);
    float* logits = (float*)carve((size_t)BATCH * VOCAB * 4);
    int* tok   = (int*)carve((size_t)BATCH * 4);

    // output layout
    float* logp = out;
    float* rnn  = out + (long)BATCH * VOCAB;
    float* dec  = rnn + (long)BATCH * PADLEN * HID;

    // prep
    init_kernel<<<(BATCH + 255) / 256, 256, 0, stream>>>(tok, dec);
    feats_split_kernel<<<BATCH, 256, 0, stream>>>(sm, fh, fl);
    {
        long n = (long)3 * HID * HID;
        split_kernel<<<(int)((n + 255) / 256), 256, 0, stream>>>(Wh, Whh, Whl, n);
    }
    {
        long n = (long)HID * 2 * SMH;
        split_kernel<<<(int)((n + 255) / 256), 256, 0, stream>>>(W_fc1, W1h, W1l, n);
    }
    gx_kernel<<<dim3(3 * HID / 256, VOCAB), 256, 0, stream>>>(emb, Wi, bi, gx);
    transpose_wout<<<(HID * VOCAB + 255) / 256, 256, 0, stream>>>(W_out, Wt);

    // h0 = relu(feats @ W_fc1^T + b_fc1), with split output for step-0 GEMM
    gemm_mfma_split<<<dim3(HID / 128, BATCH / 128), 256, 0, stream>>>(
        fh, fl, W1h, W1l, b_fc1, h, hh, hl, BATCH, HID, 2 * SMH, 1);

    // recurrent loop
    for (int t = 0; t < PADLEN; t++) {
        gemm_mfma_split<<<dim3(3 * HID / 128, BATCH / 128), 256, 0, stream>>>(
            hh, hl, Whh, Whl, bh, gh_buf, (unsigned short*)nullptr, (unsigned short*)nullptr,
            BATCH, 3 * HID, HID, 0);
        gru_elem<<<(BATCH * HID) / 256, 256, 0, stream>>>(gh_buf, gx, tok, h, hh, hl, rnn, t);
        logits_argmax<<<BATCH / 4, 256, 0, stream>>>(h, Wt, b_out, tok,
                                                     dec + (long)(t + 1) * BATCH, logits);
    }

    // final log_softmax
    log_softmax_k<<<BATCH / 4, 256, 0, stream>>>(logits, logp);
}